// Round 4
// baseline (1862.036 us; speedup 1.0000x reference)
//
#include <hip/hip_runtime.h>
#include <math.h>

#define VOCAB   50000
#define EMBED   256
#define HIDDEN  64
#define G4      256     // 4*HIDDEN
#define BATCH   64
#define TSEQ    2048
#define NUM_OUT 16

typedef _Float16 h2 __attribute__((ext_vector_type(2)));

__device__ __forceinline__ float fexp2f(float x) { return __builtin_amdgcn_exp2f(x); }
__device__ __forceinline__ float frcpf(float x)  { return __builtin_amdgcn_rcpf(x); }
__device__ __forceinline__ float fsigmoidf(float x) {
    return frcpf(1.0f + fexp2f(-1.44269504f * x));
}
// tanh(x) = 1 - 2/(2^(2x*log2e)+1); saturates correctly at +-inf
__device__ __forceinline__ float ftanhf(float x) {
    float e = fexp2f(2.88539008f * x);
    return 1.0f - 2.0f * frcpf(e + 1.0f);
}

// f16x2 dot with fp32 accumulate — v_dot2_f32_f16
__device__ __forceinline__ float dot2(h2 a, h2 b, float c) {
#if __has_builtin(__builtin_amdgcn_fdot2)
    return __builtin_amdgcn_fdot2(a, b, c, false);
#else
    float r;
    asm("v_dot2_f32_f16 %0, %1, %2, %3"
        : "=v"(r)
        : "v"(__builtin_bit_cast(int, a)), "v"(__builtin_bit_cast(int, b)), "v"(c));
    return r;
#endif
}

// xor-1 neighbor exchange as pure-VALU DPP (quad_perm [1,0,3,2] = 0xB1)
__device__ __forceinline__ int dpp_xor1(int v) {
    return __builtin_amdgcn_update_dpp(0, v, 0xB1, 0xF, 0xF, true);
}
__device__ __forceinline__ int rl(int v, int lane) {
    return __builtin_amdgcn_readlane(v, lane);
}

// ---------------------------------------------------------------------------
// proj[v][u][q] = dot(emb[v], W_ih[q*64+u]) + b_ih[q*64+u] + b_hh[q*64+u]
// B-tile row r <-> W_ih row (r&3)*64 + U0 + (r>>2): each thread owns the 4
// gates of ONE unit -> proj stores are coalesced float4 (round-3 stores were
// 4B @ stride 16B = 25% efficiency, proj_kernel was ~134us).
// ---------------------------------------------------------------------------
__global__ __launch_bounds__(256) void proj_kernel(
    const float* __restrict__ emb, const float* __restrict__ W_ih,
    const float* __restrict__ b_ih, const float* __restrict__ b_hh,
    float* __restrict__ proj)
{
    __shared__ __align__(16) float As[64][68]; // As[k][r] = emb[R0+r][kc*64+k]
    __shared__ __align__(16) float Bs[64][68]; // Bs[k][r] = W_ih[map(r)][kc*64+k]

    const int tid = threadIdx.x;
    const int R0 = blockIdx.x * 64;
    const int U0 = blockIdx.y * 16;   // 16 units per y-block (gridDim.y = 4)

    const int rr = (tid & 15) * 4;    // 4 emb rows
    const int gg = (tid >> 4) * 4;    // 4 tile-cols = gates 0..3 of unit U0+uu
    const int uu = tid >> 4;          // unit within the 16-unit group

    float acc[4][4] = {};

    for (int kc = 0; kc < 4; ++kc) {
        #pragma unroll
        for (int it = 0; it < 4; ++it) {
            int flat = (it * 256 + tid) * 4;
            int r = flat >> 6;
            int k = flat & 63;
            int row = R0 + r;
            float4 v = make_float4(0.f, 0.f, 0.f, 0.f);
            if (row < VOCAB)
                v = *(const float4*)&emb[(size_t)row * EMBED + kc * 64 + k];
            As[k + 0][r] = v.x; As[k + 1][r] = v.y;
            As[k + 2][r] = v.z; As[k + 3][r] = v.w;
            int wrow = (r & 3) * 64 + U0 + (r >> 2);   // gate (r&3), unit U0+(r>>2)
            float4 wv = *(const float4*)&W_ih[(size_t)wrow * EMBED + kc * 64 + k];
            Bs[k + 0][r] = wv.x; Bs[k + 1][r] = wv.y;
            Bs[k + 2][r] = wv.z; Bs[k + 3][r] = wv.w;
        }
        __syncthreads();

        #pragma unroll 8
        for (int k = 0; k < 64; ++k) {
            float4 a = *(const float4*)&As[k][rr];
            float4 b = *(const float4*)&Bs[k][gg];
            acc[0][0] = fmaf(a.x, b.x, acc[0][0]);
            acc[0][1] = fmaf(a.x, b.y, acc[0][1]);
            acc[0][2] = fmaf(a.x, b.z, acc[0][2]);
            acc[0][3] = fmaf(a.x, b.w, acc[0][3]);
            acc[1][0] = fmaf(a.y, b.x, acc[1][0]);
            acc[1][1] = fmaf(a.y, b.y, acc[1][1]);
            acc[1][2] = fmaf(a.y, b.z, acc[1][2]);
            acc[1][3] = fmaf(a.y, b.w, acc[1][3]);
            acc[2][0] = fmaf(a.z, b.x, acc[2][0]);
            acc[2][1] = fmaf(a.z, b.y, acc[2][1]);
            acc[2][2] = fmaf(a.z, b.z, acc[2][2]);
            acc[2][3] = fmaf(a.z, b.w, acc[2][3]);
            acc[3][0] = fmaf(a.w, b.x, acc[3][0]);
            acc[3][1] = fmaf(a.w, b.y, acc[3][1]);
            acc[3][2] = fmaf(a.w, b.z, acc[3][2]);
            acc[3][3] = fmaf(a.w, b.w, acc[3][3]);
        }
        __syncthreads();
    }

    float bias[4];
    #pragma unroll
    for (int q = 0; q < 4; ++q)
        bias[q] = b_ih[q * 64 + U0 + uu] + b_hh[q * 64 + U0 + uu];

    #pragma unroll
    for (int u = 0; u < 4; ++u) {
        int row = R0 + rr + u;
        if (row < VOCAB) {
            float4 o;
            o.x = acc[u][0] + bias[0];
            o.y = acc[u][1] + bias[1];
            o.z = acc[u][2] + bias[2];
            o.w = acc[u][3] + bias[3];
            *(float4*)&proj[(size_t)row * G4 + (U0 + uu) * 4] = o;  // coalesced
        }
    }
}

// ---------------------------------------------------------------------------
// LSTM scan, 8 independent waves per block (one batch element each) -> 2
// waves per SIMD: hardware SMT fills the dependency/hazard bubbles that
// round 3 exposed (1051 cyc/step vs ~385 issue floor with 1 wave/SIMD).
// Tokens live in registers (1 dword per lane per 64 steps + readlane),
// zero LDS in the hot loop, no cross-wave communication, no barriers.
// ---------------------------------------------------------------------------
__global__ __launch_bounds__(512, 2) void lstm_scan(
    const int* __restrict__ x, const float* __restrict__ proj,
    const float* __restrict__ W_hh,
    const float* __restrict__ bn_gamma, const float* __restrict__ bn_beta,
    const float* __restrict__ bn_mean, const float* __restrict__ bn_var,
    const float* __restrict__ fc_w, const float* __restrict__ fc_b,
    float* __restrict__ out)
{
    const int w = threadIdx.x >> 6;    // wave id 0..7
    const int j = threadIdx.x & 63;    // hidden unit
    const int b = blockIdx.x * 8 + w;  // batch element (grid = BATCH/8)

    __shared__ float hb_s[8][HIDDEN];

    // this lane's 4 W_hh rows (gates i,f,g,o for unit j) as f16 pairs
    h2 wi[32], wf[32], wg[32], wo[32];
    {
        const float* Wi = &W_hh[(size_t)(0 * HIDDEN + j) * HIDDEN];
        const float* Wf = &W_hh[(size_t)(1 * HIDDEN + j) * HIDDEN];
        const float* Wg = &W_hh[(size_t)(2 * HIDDEN + j) * HIDDEN];
        const float* Wo = &W_hh[(size_t)(3 * HIDDEN + j) * HIDDEN];
        #pragma unroll
        for (int m = 0; m < 32; ++m) {
            float2 vi = *(const float2*)&Wi[2 * m];
            float2 vf = *(const float2*)&Wf[2 * m];
            float2 vg = *(const float2*)&Wg[2 * m];
            float2 vo = *(const float2*)&Wo[2 * m];
            wi[m] = h2{(_Float16)vi.x, (_Float16)vi.y};
            wf[m] = h2{(_Float16)vf.x, (_Float16)vf.y};
            wg[m] = h2{(_Float16)vg.x, (_Float16)vg.y};
            wo[m] = h2{(_Float16)vo.x, (_Float16)vo.y};
        }
    }

    float h = 0.0f, c = 0.0f;
    int pk = 0;  // f16x2 (h_{2m}, h_{2m+1}) in even lane 2m; h=0 -> 0

    auto step = [&](const float4& gx) {
        float ai = gx.x, af = gx.y, ag = gx.z, ao = gx.w;  // gate order i,f,g,o
        float bi2 = 0.f, bf2 = 0.f, bg2 = 0.f, bo2 = 0.f;
        #pragma unroll
        for (int m = 0; m < 32; m += 2) {
            h2 hA = __builtin_bit_cast(h2, rl(pk, 2 * m));
            h2 hB = __builtin_bit_cast(h2, rl(pk, 2 * m + 2));
            ai  = dot2(wi[m],     hA, ai);
            af  = dot2(wf[m],     hA, af);
            ag  = dot2(wg[m],     hA, ag);
            ao  = dot2(wo[m],     hA, ao);
            bi2 = dot2(wi[m + 1], hB, bi2);
            bf2 = dot2(wf[m + 1], hB, bf2);
            bg2 = dot2(wg[m + 1], hB, bg2);
            bo2 = dot2(wo[m + 1], hB, bo2);
        }
        ai += bi2; af += bf2; ag += bg2; ao += bo2;
        float i_ = fsigmoidf(ai);
        float f_ = fsigmoidf(af);
        float g_ = ftanhf(ag);
        float o_ = fsigmoidf(ao);
        c = fmaf(f_, c, i_ * g_);
        h = o_ * ftanhf(c);
        int hp = dpp_xor1(__float_as_int(h));
        pk = __builtin_bit_cast(int, __builtin_amdgcn_cvt_pkrtz(h, __int_as_float(hp)));
    };

    // tokens: lane l of chunk ch holds x[b*TSEQ + ch*64 + l]; readlane extracts
    const int* xb = &x[(size_t)b * TSEQ];
    int tv_cur = xb[j];
    int tv_nxt = xb[64 + j];

    // prologue: gx for t=0,1 in flight; tokens for t=2,3 staged
    float4 g0 = *(const float4*)&proj[(size_t)rl(tv_cur, 0) * G4 + j * 4];
    float4 g1 = *(const float4*)&proj[(size_t)rl(tv_cur, 1) * G4 + j * 4];
    int tk0 = rl(tv_cur, 2), tk1 = rl(tv_cur, 3);

    for (int t = 0; t < TSEQ; t += 2) {
        if ((t & 63) == 0 && t) {            // chunk boundary (uniform, 1/32)
            tv_cur = tv_nxt;
            int cn = (t >> 6) + 1;
            if (cn > TSEQ / 64 - 1) cn = TSEQ / 64 - 1;
            tv_nxt = xb[cn * 64 + j];
        }
        // tokens t+4, t+5 (clamped; dead-load tokens just need to be valid)
        int u0 = t + 4 < TSEQ ? t + 4 : TSEQ - 1;
        int u1 = t + 5 < TSEQ ? t + 5 : TSEQ - 1;
        int s0 = ((u0 >> 6) == (t >> 6)) ? tv_cur : tv_nxt;
        int s1 = ((u1 >> 6) == (t >> 6)) ? tv_cur : tv_nxt;
        int nk0 = rl(s0, u0 & 63);
        int nk1 = rl(s1, u1 & 63);

        float4 n0 = *(const float4*)&proj[(size_t)tk0 * G4 + j * 4];
        step(g0);
        float4 n1 = *(const float4*)&proj[(size_t)tk1 * G4 + j * 4];
        step(g1);
        g0 = n0; g1 = n1; tk0 = nk0; tk1 = nk1;
    }

    // epilogue: BatchNorm (running stats) then FC
    float hb = (h - bn_mean[j]) * rsqrtf(bn_var[j] + 1e-5f) * bn_gamma[j]
               + bn_beta[j];
    hb_s[w][j] = hb;
    __syncthreads();
    if (j < NUM_OUT) {
        float s0 = fc_b[j], s1 = 0.f, s2 = 0.f, s3 = 0.f;
        #pragma unroll
        for (int k = 0; k < HIDDEN; k += 4) {
            s0 = fmaf(hb_s[w][k + 0], fc_w[j * HIDDEN + k + 0], s0);
            s1 = fmaf(hb_s[w][k + 1], fc_w[j * HIDDEN + k + 1], s1);
            s2 = fmaf(hb_s[w][k + 2], fc_w[j * HIDDEN + k + 2], s2);
            s3 = fmaf(hb_s[w][k + 3], fc_w[j * HIDDEN + k + 3], s3);
        }
        out[b * NUM_OUT + j] = (s0 + s1) + (s2 + s3);
    }
}

// ---------------------------------------------------------------------------
extern "C" void kernel_launch(void* const* d_in, const int* in_sizes, int n_in,
                              void* d_out, int out_size, void* d_ws, size_t ws_size,
                              hipStream_t stream) {
    const int*   x        = (const int*)d_in[0];
    // d_in[1] = seq_lengths: unused by the reference computation
    const float* emb      = (const float*)d_in[2];
    const float* W_ih     = (const float*)d_in[3];
    const float* W_hh     = (const float*)d_in[4];
    const float* b_ih     = (const float*)d_in[5];
    const float* b_hh     = (const float*)d_in[6];
    const float* bn_gamma = (const float*)d_in[7];
    const float* bn_beta  = (const float*)d_in[8];
    const float* bn_mean  = (const float*)d_in[9];
    const float* bn_var   = (const float*)d_in[10];
    const float* fc_w     = (const float*)d_in[11];
    const float* fc_b     = (const float*)d_in[12];

    float* proj = (float*)d_ws;  // VOCAB * 256 * 4 B = 51.2 MB

    dim3 pgrid((VOCAB + 63) / 64, G4 / 64);
    proj_kernel<<<pgrid, 256, 0, stream>>>(emb, W_ih, b_ih, b_hh, proj);

    lstm_scan<<<BATCH / 8, 512, 0, stream>>>(x, proj, W_hh,
                                             bn_gamma, bn_beta, bn_mean, bn_var,
                                             fc_w, fc_b, (float*)d_out);
}

// Round 5
// 1001.492 us; speedup vs baseline: 1.8593x; 1.8593x over previous
//
#include <hip/hip_runtime.h>
#include <math.h>

#define VOCAB   50000
#define EMBED   256
#define HIDDEN  64
#define G4      256     // 4*HIDDEN
#define BATCH   64
#define TSEQ    2048
#define NUM_OUT 16

typedef _Float16 h2 __attribute__((ext_vector_type(2)));

__device__ __forceinline__ float fexp2f(float x) { return __builtin_amdgcn_exp2f(x); }
__device__ __forceinline__ float frcpf(float x)  { return __builtin_amdgcn_rcpf(x); }
__device__ __forceinline__ float fsigmoidf(float x) {
    return frcpf(1.0f + fexp2f(-1.44269504f * x));
}
// tanh(x) = 1 - 2/(2^(2x*log2e)+1); saturates correctly at +-inf
__device__ __forceinline__ float ftanhf(float x) {
    float e = fexp2f(2.88539008f * x);
    return 1.0f - 2.0f * frcpf(e + 1.0f);
}

// f16x2 dot with fp32 accumulate — v_dot2_f32_f16
__device__ __forceinline__ float dot2(h2 a, h2 b, float c) {
#if __has_builtin(__builtin_amdgcn_fdot2)
    return __builtin_amdgcn_fdot2(a, b, c, false);
#else
    float r;
    asm("v_dot2_f32_f16 %0, %1, %2, %3"
        : "=v"(r)
        : "v"(__builtin_bit_cast(int, a)), "v"(__builtin_bit_cast(int, b)), "v"(c));
    return r;
#endif
}

// xor-1 neighbor exchange as pure-VALU DPP (quad_perm [1,0,3,2] = 0xB1)
__device__ __forceinline__ int dpp_xor1(int v) {
    return __builtin_amdgcn_update_dpp(0, v, 0xB1, 0xF, 0xF, true);
}
__device__ __forceinline__ int rl(int v, int lane) {
    return __builtin_amdgcn_readlane(v, lane);
}

#define REP32(M) M(0) M(1) M(2) M(3) M(4) M(5) M(6) M(7) \
                 M(8) M(9) M(10) M(11) M(12) M(13) M(14) M(15) \
                 M(16) M(17) M(18) M(19) M(20) M(21) M(22) M(23) \
                 M(24) M(25) M(26) M(27) M(28) M(29) M(30) M(31)

// ---------------------------------------------------------------------------
// proj[v][u][q] = dot(emb[v], W_ih[q*64+u]) + b_ih[q*64+u] + b_hh[q*64+u]
// Each thread owns the 4 gates of ONE unit -> coalesced float4 stores.
// ---------------------------------------------------------------------------
__global__ __launch_bounds__(256) void proj_kernel(
    const float* __restrict__ emb, const float* __restrict__ W_ih,
    const float* __restrict__ b_ih, const float* __restrict__ b_hh,
    float* __restrict__ proj)
{
    __shared__ __align__(16) float As[64][68]; // As[k][r] = emb[R0+r][kc*64+k]
    __shared__ __align__(16) float Bs[64][68]; // Bs[k][r] = W_ih[map(r)][kc*64+k]

    const int tid = threadIdx.x;
    const int R0 = blockIdx.x * 64;
    const int U0 = blockIdx.y * 16;   // 16 units per y-block (gridDim.y = 4)

    const int rr = (tid & 15) * 4;    // 4 emb rows
    const int gg = (tid >> 4) * 4;    // 4 tile-cols = gates 0..3 of unit U0+uu
    const int uu = tid >> 4;          // unit within the 16-unit group

    float acc[4][4] = {};

    for (int kc = 0; kc < 4; ++kc) {
        #pragma unroll
        for (int it = 0; it < 4; ++it) {
            int flat = (it * 256 + tid) * 4;
            int r = flat >> 6;
            int k = flat & 63;
            int row = R0 + r;
            float4 v = make_float4(0.f, 0.f, 0.f, 0.f);
            if (row < VOCAB)
                v = *(const float4*)&emb[(size_t)row * EMBED + kc * 64 + k];
            As[k + 0][r] = v.x; As[k + 1][r] = v.y;
            As[k + 2][r] = v.z; As[k + 3][r] = v.w;
            int wrow = (r & 3) * 64 + U0 + (r >> 2);   // gate (r&3), unit U0+(r>>2)
            float4 wv = *(const float4*)&W_ih[(size_t)wrow * EMBED + kc * 64 + k];
            Bs[k + 0][r] = wv.x; Bs[k + 1][r] = wv.y;
            Bs[k + 2][r] = wv.z; Bs[k + 3][r] = wv.w;
        }
        __syncthreads();

        #pragma unroll 8
        for (int k = 0; k < 64; ++k) {
            float4 a = *(const float4*)&As[k][rr];
            float4 b = *(const float4*)&Bs[k][gg];
            acc[0][0] = fmaf(a.x, b.x, acc[0][0]);
            acc[0][1] = fmaf(a.x, b.y, acc[0][1]);
            acc[0][2] = fmaf(a.x, b.z, acc[0][2]);
            acc[0][3] = fmaf(a.x, b.w, acc[0][3]);
            acc[1][0] = fmaf(a.y, b.x, acc[1][0]);
            acc[1][1] = fmaf(a.y, b.y, acc[1][1]);
            acc[1][2] = fmaf(a.y, b.z, acc[1][2]);
            acc[1][3] = fmaf(a.y, b.w, acc[1][3]);
            acc[2][0] = fmaf(a.z, b.x, acc[2][0]);
            acc[2][1] = fmaf(a.z, b.y, acc[2][1]);
            acc[2][2] = fmaf(a.z, b.z, acc[2][2]);
            acc[2][3] = fmaf(a.z, b.w, acc[2][3]);
            acc[3][0] = fmaf(a.w, b.x, acc[3][0]);
            acc[3][1] = fmaf(a.w, b.y, acc[3][1]);
            acc[3][2] = fmaf(a.w, b.z, acc[3][2]);
            acc[3][3] = fmaf(a.w, b.w, acc[3][3]);
        }
        __syncthreads();
    }

    float bias[4];
    #pragma unroll
    for (int q = 0; q < 4; ++q)
        bias[q] = b_ih[q * 64 + U0 + uu] + b_hh[q * 64 + U0 + uu];

    #pragma unroll
    for (int u = 0; u < 4; ++u) {
        int row = R0 + rr + u;
        if (row < VOCAB) {
            float4 o;
            o.x = acc[u][0] + bias[0];
            o.y = acc[u][1] + bias[1];
            o.z = acc[u][2] + bias[2];
            o.w = acc[u][3] + bias[3];
            *(float4*)&proj[(size_t)row * G4 + (U0 + uu) * 4] = o;  // coalesced
        }
    }
}

// ---------------------------------------------------------------------------
// Barrier-free LSTM scan: ONE wave per batch element, 64 CUs. The 128 weight
// registers are NAMED SSA values (macro-generated, no indexable array) so
// they cannot be demoted to scratch — rounds 2-4 showed VGPR_Count 88-96,
// i.e. the w[] arrays lived in scratch and cost ~600 issue-cycles/step in
// per-lane buffer_loads. Zero LDS / zero barriers in the hot loop.
// ---------------------------------------------------------------------------
__global__ __launch_bounds__(64, 1) void lstm_scan(
    const int* __restrict__ x, const float* __restrict__ proj,
    const float* __restrict__ W_hh,
    const float* __restrict__ bn_gamma, const float* __restrict__ bn_beta,
    const float* __restrict__ bn_mean, const float* __restrict__ bn_var,
    const float* __restrict__ fc_w, const float* __restrict__ fc_b,
    float* __restrict__ out)
{
    const int b = blockIdx.x;
    const int j = threadIdx.x;   // 0..63, hidden unit index

    __shared__ int   toks[TSEQ];
    __shared__ float hb_s[HIDDEN];

    for (int i = j; i < TSEQ; i += 64) toks[i] = x[b * TSEQ + i];
    __syncthreads();

    const float* Wi = &W_hh[(size_t)(0 * HIDDEN + j) * HIDDEN];
    const float* Wf = &W_hh[(size_t)(1 * HIDDEN + j) * HIDDEN];
    const float* Wg = &W_hh[(size_t)(2 * HIDDEN + j) * HIDDEN];
    const float* Wo = &W_hh[(size_t)(3 * HIDDEN + j) * HIDDEN];

    // 128 named h2 registers: wi0..wi31, wf0..wf31, wg0..wg31, wo0..wo31
#define W_DECL(n) h2 wi##n, wf##n, wg##n, wo##n;
    REP32(W_DECL)
#undef W_DECL

#define W_LOAD(n) { \
        float2 vi = *(const float2*)&Wi[2 * (n)]; \
        float2 vf = *(const float2*)&Wf[2 * (n)]; \
        float2 vg = *(const float2*)&Wg[2 * (n)]; \
        float2 vo = *(const float2*)&Wo[2 * (n)]; \
        wi##n = h2{(_Float16)vi.x, (_Float16)vi.y}; \
        wf##n = h2{(_Float16)vf.x, (_Float16)vf.y}; \
        wg##n = h2{(_Float16)vg.x, (_Float16)vg.y}; \
        wo##n = h2{(_Float16)vo.x, (_Float16)vo.y}; }
    REP32(W_LOAD)
#undef W_LOAD

    float h = 0.0f, c = 0.0f;
    int pk = 0;  // f16x2 (h_{2m}, h_{2m+1}) in even lane 2m; h=0 -> 0

    auto step = [&](const float4& gx) {
        float ai = gx.x, af = gx.y, ag = gx.z, ao = gx.w;  // gate order i,f,g,o
        float bi = 0.f, bf = 0.f, bg = 0.f, bo = 0.f;
        // 32 broadcasts (even lanes hold packed h pairs), 8 accumulation chains
#define W_DOT(n) { \
            h2 hh = __builtin_bit_cast(h2, rl(pk, 2 * (n))); \
            if ((n) & 1) { \
                bi = dot2(wi##n, hh, bi); bf = dot2(wf##n, hh, bf); \
                bg = dot2(wg##n, hh, bg); bo = dot2(wo##n, hh, bo); \
            } else { \
                ai = dot2(wi##n, hh, ai); af = dot2(wf##n, hh, af); \
                ag = dot2(wg##n, hh, ag); ao = dot2(wo##n, hh, ao); \
            } }
        REP32(W_DOT)
#undef W_DOT
        ai += bi; af += bf; ag += bg; ao += bo;
        float i_ = fsigmoidf(ai);
        float f_ = fsigmoidf(af);
        float g_ = ftanhf(ag);
        float o_ = fsigmoidf(ao);
        c = fmaf(f_, c, i_ * g_);
        h = o_ * ftanhf(c);
        int hp = dpp_xor1(__float_as_int(h));
        pk = __builtin_bit_cast(int, __builtin_amdgcn_cvt_pkrtz(h, __int_as_float(hp)));
    };

    // 2-step-deep gx prefetch, tokens one unroll-iter ahead
    float4 g0 = *(const float4*)&proj[(size_t)toks[0] * G4 + j * 4];
    float4 g1 = *(const float4*)&proj[(size_t)toks[1] * G4 + j * 4];
    int tk0 = toks[2], tk1 = toks[3];

    for (int t = 0; t < TSEQ; t += 2) {
        int i4 = (t + 4 < TSEQ) ? t + 4 : TSEQ - 1;
        int i5 = (t + 5 < TSEQ) ? t + 5 : TSEQ - 1;
        int nk0 = toks[i4];
        int nk1 = toks[i5];
        float4 n0 = *(const float4*)&proj[(size_t)tk0 * G4 + j * 4];
        step(g0);
        float4 n1 = *(const float4*)&proj[(size_t)tk1 * G4 + j * 4];
        step(g1);
        g0 = n0; g1 = n1; tk0 = nk0; tk1 = nk1;
    }

    // epilogue: BatchNorm (running stats) then FC
    float hb = (h - bn_mean[j]) * rsqrtf(bn_var[j] + 1e-5f) * bn_gamma[j]
               + bn_beta[j];
    hb_s[j] = hb;
    __syncthreads();
    if (j < NUM_OUT) {
        float s0 = fc_b[j], s1 = 0.f, s2 = 0.f, s3 = 0.f;
        #pragma unroll
        for (int k = 0; k < HIDDEN; k += 4) {
            s0 = fmaf(hb_s[k + 0], fc_w[j * HIDDEN + k + 0], s0);
            s1 = fmaf(hb_s[k + 1], fc_w[j * HIDDEN + k + 1], s1);
            s2 = fmaf(hb_s[k + 2], fc_w[j * HIDDEN + k + 2], s2);
            s3 = fmaf(hb_s[k + 3], fc_w[j * HIDDEN + k + 3], s3);
        }
        out[b * NUM_OUT + j] = (s0 + s1) + (s2 + s3);
    }
}

// ---------------------------------------------------------------------------
extern "C" void kernel_launch(void* const* d_in, const int* in_sizes, int n_in,
                              void* d_out, int out_size, void* d_ws, size_t ws_size,
                              hipStream_t stream) {
    const int*   x        = (const int*)d_in[0];
    // d_in[1] = seq_lengths: unused by the reference computation
    const float* emb      = (const float*)d_in[2];
    const float* W_ih     = (const float*)d_in[3];
    const float* W_hh     = (const float*)d_in[4];
    const float* b_ih     = (const float*)d_in[5];
    const float* b_hh     = (const float*)d_in[6];
    const float* bn_gamma = (const float*)d_in[7];
    const float* bn_beta  = (const float*)d_in[8];
    const float* bn_mean  = (const float*)d_in[9];
    const float* bn_var   = (const float*)d_in[10];
    const float* fc_w     = (const float*)d_in[11];
    const float* fc_b     = (const float*)d_in[12];

    float* proj = (float*)d_ws;  // VOCAB * 256 * 4 B = 51.2 MB

    dim3 pgrid((VOCAB + 63) / 64, G4 / 64);
    proj_kernel<<<pgrid, 256, 0, stream>>>(emb, W_ih, b_ih, b_hh, proj);

    lstm_scan<<<BATCH, 64, 0, stream>>>(x, proj, W_hh,
                                        bn_gamma, bn_beta, bn_mean, bn_var,
                                        fc_w, fc_b, (float*)d_out);
}